// Round 2
// baseline (647.393 us; speedup 1.0000x reference)
//
#include <hip/hip_runtime.h>

// ---------------- kernels ----------------

__global__ void k_init(int* __restrict__ deg, int* __restrict__ fill,
                       float* __restrict__ gsum, int n) {
    int i = blockIdx.x * blockDim.x + threadIdx.x;
    if (i < n) { deg[i] = 1; fill[i] = 0; }          // deg starts at 1 (self-loop)
    if (blockIdx.x == 0 && threadIdx.x < 32) gsum[threadIdx.x] = 0.f;
}

// histogram of in-degree over col = edge_index[1]  (int32 per harness contract)
__global__ void k_count(const int* __restrict__ col, int* __restrict__ deg, int E, int n) {
    int stride = gridDim.x * blockDim.x;
    for (int e = blockIdx.x * blockDim.x + threadIdx.x; e < E; e += stride) {
        int c = col[e];
        if ((unsigned)c < (unsigned)n) atomicAdd(&deg[c], 1);
    }
}

// dis = rsqrt(deg); per-block sum of edge counts (deg-1) for the scan
__global__ void k_dis_blocksum(const int* __restrict__ deg, float* __restrict__ dis,
                               int* __restrict__ partial, int n) {
    __shared__ int s[256];
    int i = blockIdx.x * 256 + threadIdx.x;
    int c = 0;
    if (i < n) { int d = deg[i]; dis[i] = rsqrtf((float)d); c = d - 1; }
    s[threadIdx.x] = c;
    __syncthreads();
    for (int st = 128; st > 0; st >>= 1) {
        if (threadIdx.x < st) s[threadIdx.x] += s[threadIdx.x + st];
        __syncthreads();
    }
    if (threadIdx.x == 0) partial[blockIdx.x] = s[0];
}

// exclusive scan of block partials (nb <= 512), single block of 512
__global__ void k_scan_partials(int* __restrict__ partial, int nb) {
    __shared__ int s[512];
    int t = threadIdx.x;
    int val = (t < nb) ? partial[t] : 0;
    s[t] = val;
    __syncthreads();
    for (int off = 1; off < 512; off <<= 1) {
        int v = (t >= off) ? s[t - off] : 0;
        __syncthreads();
        s[t] += v;
        __syncthreads();
    }
    if (t < nb) partial[t] = s[t] - val;   // exclusive
}

// ptr[v] = block-exclusive-scan(deg-1) + partial[block]
__global__ void k_ptr(const int* __restrict__ deg, const int* __restrict__ partial,
                      int* __restrict__ ptr, int n) {
    __shared__ int s[256];
    int i = blockIdx.x * 256 + threadIdx.x;
    int c = (i < n) ? (deg[i] - 1) : 0;
    int val = c;
    s[threadIdx.x] = c;
    __syncthreads();
    for (int off = 1; off < 256; off <<= 1) {
        int v = (threadIdx.x >= off) ? s[threadIdx.x - off] : 0;
        __syncthreads();
        s[threadIdx.x] += v;
        __syncthreads();
    }
    if (i < n) ptr[i] = s[threadIdx.x] - val + partial[blockIdx.x];
}

// scatter edge sources into CSR slots keyed by col
__global__ void k_scatter(const int* __restrict__ row, const int* __restrict__ col,
                          const int* __restrict__ ptr, int* __restrict__ fill,
                          int* __restrict__ csr, int E, int n) {
    int stride = gridDim.x * blockDim.x;
    for (int e = blockIdx.x * blockDim.x + threadIdx.x; e < E; e += stride) {
        int r = row[e];
        int c = col[e];
        if ((unsigned)r >= (unsigned)n || (unsigned)c >= (unsigned)n) continue;
        int pos = ptr[c] + atomicAdd(&fill[c], 1);
        csr[pos] = r;
    }
}

// zs1[v] = x[v] * dis[v]   (4 features, float4)
__global__ void k_zs1(const float4* __restrict__ x, const float* __restrict__ dis,
                      float4* __restrict__ zs1, int n) {
    int i = blockIdx.x * blockDim.x + threadIdx.x;
    if (i < n) {
        float d = dis[i];
        float4 v = x[i];
        v.x *= d; v.y *= d; v.z *= d; v.w *= d;
        zs1[i] = v;
    }
}

// p1[v] = dis[v] * ( zs1[v] + sum_{u in in(v)} zs1[u] )
__global__ void k_prop1(const float4* __restrict__ zs, const int* __restrict__ csr,
                        const int* __restrict__ ptr, const int* __restrict__ deg,
                        const float* __restrict__ dis, float4* __restrict__ p1, int n) {
    int v = blockIdx.x * blockDim.x + threadIdx.x;
    if (v >= n) return;
    int beg = ptr[v], cnt = deg[v] - 1;
    float4 a = zs[v];
    for (int k = 0; k < cnt; k++) {
        float4 u = zs[csr[beg + k]];
        a.x += u.x; a.y += u.y; a.z += u.z; a.w += u.w;
    }
    float d = dis[v];
    a.x *= d; a.y *= d; a.z *= d; a.w *= d;
    p1[v] = a;
}

// per node: t = relu(p1 @ W1 + b1) [64];  zs2 = (t @ W2) * dis  [32]
__global__ __launch_bounds__(256) void k_mlp(const float4* __restrict__ p1,
        const float* __restrict__ W1, const float* __restrict__ b1,
        const float* __restrict__ W2, const float* __restrict__ dis,
        float* __restrict__ zs2, int n) {
    __shared__ float sW1[4 * 64];
    __shared__ float sb1[64];
    __shared__ float sW2[64 * 32];
    for (int i = threadIdx.x; i < 256; i += 256) sW1[i] = W1[i];
    if (threadIdx.x < 64) sb1[threadIdx.x] = b1[threadIdx.x];
    for (int i = threadIdx.x; i < 2048; i += 256) sW2[i] = W2[i];
    __syncthreads();
    int v = blockIdx.x * blockDim.x + threadIdx.x;
    if (v >= n) return;
    float4 p = p1[v];
    float acc[32];
#pragma unroll
    for (int j = 0; j < 32; j++) acc[j] = 0.f;
    for (int k = 0; k < 64; k++) {
        float t = fmaxf(p.x * sW1[k] + p.y * sW1[64 + k] + p.z * sW1[128 + k]
                        + p.w * sW1[192 + k] + sb1[k], 0.f);
#pragma unroll
        for (int j = 0; j < 32; j++) acc[j] += t * sW2[k * 32 + j];
    }
    float d = dis[v];
#pragma unroll
    for (int j = 0; j < 32; j++) zs2[(size_t)v * 32 + j] = acc[j] * d;
}

// prop layer 2 (32 lanes per node) + relu(+b2) + global mean-pool partial sums
__global__ __launch_bounds__(256) void k_prop2(const float* __restrict__ zs2,
        const int* __restrict__ csr, const int* __restrict__ ptr, const int* __restrict__ deg,
        const float* __restrict__ dis, const float* __restrict__ b2,
        float* __restrict__ gsum, int n) {
    __shared__ float gacc[32];
    if (threadIdx.x < 32) gacc[threadIdx.x] = 0.f;
    __syncthreads();
    int f = threadIdx.x & 31;
    int v = (blockIdx.x * blockDim.x + threadIdx.x) >> 5;
    if (v < n) {
        int beg = ptr[v], cnt = deg[v] - 1;
        float a = zs2[(size_t)v * 32 + f];
        for (int k = 0; k < cnt; k++) {
            int u = csr[beg + k];
            a += zs2[(size_t)u * 32 + f];
        }
        a = fmaxf(a * dis[v] + b2[f], 0.f);
        atomicAdd(&gacc[f], a);
    }
    __syncthreads();
    if (threadIdx.x < 32) atomicAdd(&gsum[threadIdx.x], gacc[threadIdx.x]);
}

// out = sigmoid( (gsum/n) @ Wfc + bfc )
__global__ void k_final(const float* __restrict__ gsum, const float* __restrict__ Wfc,
                        const float* __restrict__ bfc, float* __restrict__ out, int n) {
    __shared__ float s[32];
    int t = threadIdx.x;
    if (t < 32) s[t] = (gsum[t] / (float)n) * Wfc[t];
    __syncthreads();
    if (t == 0) {
        float a = 0.f;
        for (int i = 0; i < 32; i++) a += s[i];
        a += bfc[0];
        out[0] = 1.f / (1.f + expf(-a));
    }
}

// ---------------- launch ----------------

extern "C" void kernel_launch(void* const* d_in, const int* in_sizes, int n_in,
                              void* d_out, int out_size, void* d_ws, size_t ws_size,
                              hipStream_t stream) {
    const float* x    = (const float*)d_in[0];
    const int*   ei   = (const int*)d_in[1];     // int32! harness converts int64 -> int32
    const float* W1   = (const float*)d_in[2];
    const float* b1   = (const float*)d_in[3];
    const float* W2   = (const float*)d_in[4];
    const float* b2   = (const float*)d_in[5];
    const float* Wfc  = (const float*)d_in[6];
    const float* bfc  = (const float*)d_in[7];
    float* out = (float*)d_out;

    const int N = in_sizes[0] / 4;
    const int E = in_sizes[1] / 2;

    auto align = [](size_t v) { return (v + 255) & ~(size_t)255; };
    char* w = (char*)d_ws;
    int*   deg     = (int*)w;    w += align((size_t)N * 4);
    int*   fill    = (int*)w;    w += align((size_t)N * 4);
    float* dis     = (float*)w;  w += align((size_t)N * 4);
    int*   ptr     = (int*)w;    w += align((size_t)N * 4);
    int*   partial = (int*)w;    w += align(512 * 4);
    int*   csr     = (int*)w;    w += align((size_t)E * 4);
    float* zs1     = (float*)w;  w += align((size_t)N * 16);
    float* p1      = (float*)w;  w += align((size_t)N * 16);
    float* zs2     = (float*)w;  w += align((size_t)N * 32 * 4);
    float* gsum    = (float*)w;  w += align(32 * 4);

    const int nb = (N + 255) / 256;   // 391 for N=100000 (<=512)

    k_init<<<nb, 256, 0, stream>>>(deg, fill, gsum, N);
    k_count<<<2048, 256, 0, stream>>>(ei + E, deg, E, N);
    k_dis_blocksum<<<nb, 256, 0, stream>>>(deg, dis, partial, N);
    k_scan_partials<<<1, 512, 0, stream>>>(partial, nb);
    k_ptr<<<nb, 256, 0, stream>>>(deg, partial, ptr, N);
    k_scatter<<<2048, 256, 0, stream>>>(ei, ei + E, ptr, fill, csr, E, N);
    k_zs1<<<nb, 256, 0, stream>>>((const float4*)x, dis, (float4*)zs1, N);
    k_prop1<<<nb, 256, 0, stream>>>((const float4*)zs1, csr, ptr, deg, dis, (float4*)p1, N);
    k_mlp<<<nb, 256, 0, stream>>>((const float4*)p1, W1, b1, W2, dis, zs2, N);
    k_prop2<<<(N * 32 + 255) / 256, 256, 0, stream>>>(zs2, csr, ptr, deg, dis, b2, gsum, N);
    k_final<<<1, 64, 0, stream>>>(gsum, Wfc, bfc, out, N);
}